// Round 1
// baseline (361.982 us; speedup 1.0000x reference)
//
#include <hip/hip_runtime.h>

// ---------------------------------------------------------------------------
// threebody indices (MatterSim): see reference. All outputs int32.
// ws layout (int32):
//   [0, A)            counts
//   [A, 2A)           cursor
//   [2A, 2A+S)        ns_acc (per-structure triple sums)
//   [2A+S, 3A+S)      starts   (exclusive scan of counts)
//   [3A+S, 4A+S)      tstarts  (exclusive scan of counts*(counts-1))
//   [4A+S, 4A+S+n_bond) sorted_bond (kept bond ids grouped by central atom)
// ---------------------------------------------------------------------------

__global__ void k_init(int* __restrict__ p, int n) {
    int i = blockIdx.x * blockDim.x + threadIdx.x;
    if (i < n) p[i] = 0;
}

__global__ void k_count(const int* __restrict__ bai, const float* __restrict__ blen,
                        const float* __restrict__ cutp, int* __restrict__ counts,
                        int n_bond) {
    int b = blockIdx.x * blockDim.x + threadIdx.x;
    if (b >= n_bond) return;
    if (blen[b] <= *cutp) atomicAdd(&counts[bai[2 * b]], 1);
}

// Single-block dual exclusive scan over A elements:
//   starts[i]  = sum_{k<i} counts[k]
//   tstarts[i] = sum_{k<i} counts[k]*(counts[k]-1)
__global__ __launch_bounds__(1024) void k_scan(const int* __restrict__ counts,
                                               int* __restrict__ starts,
                                               int* __restrict__ tstarts, int A) {
    const int T = 1024;
    __shared__ int sc[T];
    __shared__ int st[T];
    int tid = threadIdx.x;
    int chunk = (A + T - 1) / T;
    int lo = tid * chunk;
    int hi = lo + chunk;
    if (hi > A) hi = A;

    int pc = 0, pt = 0;
    for (int i = lo; i < hi; ++i) {
        int c = counts[i];
        pc += c;
        pt += c * (c - 1);
    }
    sc[tid] = pc;
    st[tid] = pt;
    __syncthreads();
    // Hillis-Steele inclusive scan over the 1024 partials
    for (int off = 1; off < T; off <<= 1) {
        int vc = 0, vt = 0;
        if (tid >= off) { vc = sc[tid - off]; vt = st[tid - off]; }
        __syncthreads();
        sc[tid] += vc;
        st[tid] += vt;
        __syncthreads();
    }
    int rc = sc[tid] - pc;   // exclusive base for this thread's chunk
    int rt = st[tid] - pt;
    for (int i = lo; i < hi; ++i) {
        int c = counts[i];
        starts[i] = rc;
        tstarts[i] = rt;
        rc += c;
        rt += c * (c - 1);
    }
}

__global__ void k_scatter(const int* __restrict__ bai, const float* __restrict__ blen,
                          const float* __restrict__ cutp, const int* __restrict__ counts,
                          const int* __restrict__ starts, int* __restrict__ cursor,
                          int* __restrict__ sorted_bond, int* __restrict__ out_ij,
                          int n_bond) {
    int b = blockIdx.x * blockDim.x + threadIdx.x;
    if (b >= n_bond) return;
    if (blen[b] <= *cutp) {
        int c = bai[2 * b];
        int cnt = counts[c];
        out_ij[b] = cnt > 1 ? cnt - 1 : 0;
        int r = atomicAdd(&cursor[c], 1);
        sorted_bond[starts[c] + r] = b;
    } else {
        out_ij[b] = 0;
    }
}

// One thread per atom: n_triple_i, per-struct sum, sort segment (restores
// deterministic ascending bond-id order), emit pair blocks into d_out.
__global__ void k_atoms(const int* __restrict__ counts, const int* __restrict__ starts,
                        const int* __restrict__ tstarts, int* __restrict__ sorted_bond,
                        const int* __restrict__ n_atoms, int n_struct,
                        int* __restrict__ ns_acc, int* __restrict__ out_ti,
                        int* __restrict__ out_bi, int A) {
    int a = blockIdx.x * blockDim.x + threadIdx.x;
    if (a >= A) return;
    int c = counts[a];
    int ti = c * (c - 1);
    out_ti[a] = ti;

    // structure id of atom a (n_struct is small, e.g. 8)
    int cum = 0, s = 0;
    for (s = 0; s < n_struct; ++s) {
        cum += n_atoms[s];
        if (a < cum) break;
    }
    if (ti > 0) atomicAdd(&ns_acc[s], ti);
    if (c < 2) return;

    int st0 = starts[a];
    // insertion sort ascending (c is small, ~10-30)
    for (int i = 1; i < c; ++i) {
        int v = sorted_bond[st0 + i];
        int j = i - 1;
        while (j >= 0 && sorted_bond[st0 + j] > v) {
            sorted_bond[st0 + j + 1] = sorted_bond[st0 + j];
            --j;
        }
        sorted_bond[st0 + j + 1] = v;
    }

    int P = ti >> 1;                 // c*(c-1)/2 combos
    long long base = 2LL * (long long)tstarts[a];
    int p = 0;
    for (int i = 0; i < c; ++i) {
        int bi = sorted_bond[st0 + i];
        for (int j = i + 1; j < c; ++j) {
            int bj = sorted_bond[st0 + j];
            long long f = base + 2LL * p;          // forward block
            long long g = base + 2LL * (P + p);    // flipped block
            out_bi[f] = bi;
            out_bi[f + 1] = bj;
            out_bi[g] = bj;
            out_bi[g + 1] = bi;
            ++p;
        }
    }
}

__global__ void k_copy_ns(const int* __restrict__ ns_acc, int* __restrict__ out_ns, int S) {
    int i = blockIdx.x * blockDim.x + threadIdx.x;
    if (i < S) out_ns[i] = ns_acc[i];
}

extern "C" void kernel_launch(void* const* d_in, const int* in_sizes, int n_in,
                              void* d_out, int out_size, void* d_ws, size_t ws_size,
                              hipStream_t stream) {
    const int* bai      = (const int*)d_in[0];    // [n_bond,2] int32
    const float* blen   = (const float*)d_in[1];  // [n_bond] f32
    const int* n_atoms  = (const int*)d_in[2];    // [S] int32
    // d_in[3] = atomic_number (unused)
    const float* cutp   = (const float*)d_in[4];  // scalar f32

    int n_bond = in_sizes[1];
    int S      = in_sizes[2];
    int A      = in_sizes[3];

    int n_tr2 = out_size - n_bond - A - S;  // 2 * n_triple

    int* out     = (int*)d_out;
    int* out_bi  = out;                 // [n_triple, 2]
    int* out_ij  = out + n_tr2;         // [n_bond]
    int* out_ti  = out_ij + n_bond;     // [A]
    int* out_ns  = out_ti + A;          // [S]

    int* ws          = (int*)d_ws;
    int* counts      = ws;
    int* cursor      = ws + A;
    int* ns_acc      = ws + 2 * A;
    int* starts      = ws + 2 * A + S;
    int* tstarts     = ws + 3 * A + S;
    int* sorted_bond = ws + 4 * A + S;

    int zn = 2 * A + S;  // counts + cursor + ns_acc are contiguous
    k_init<<<(zn + 255) / 256, 256, 0, stream>>>(ws, zn);
    k_count<<<(n_bond + 255) / 256, 256, 0, stream>>>(bai, blen, cutp, counts, n_bond);
    k_scan<<<1, 1024, 0, stream>>>(counts, starts, tstarts, A);
    k_scatter<<<(n_bond + 255) / 256, 256, 0, stream>>>(bai, blen, cutp, counts, starts,
                                                        cursor, sorted_bond, out_ij, n_bond);
    k_atoms<<<(A + 255) / 256, 256, 0, stream>>>(counts, starts, tstarts, sorted_bond,
                                                 n_atoms, S, ns_acc, out_ti, out_bi, A);
    k_copy_ns<<<1, 64, 0, stream>>>(ns_acc, out_ns, S);
}

// Round 3
// 308.512 us; speedup vs baseline: 1.1733x; 1.1733x over previous
//
#include <hip/hip_runtime.h>

// ---------------------------------------------------------------------------
// threebody indices (MatterSim). All outputs int32.
// ws layout (int32):
//   [0, A)              counts
//   [A, 2A)             cursor
//   [2A, 2A+S)          ns_acc (per-structure triple sums)
//   [2A+S, 3A+S)        starts   (exclusive scan of counts)
//   [3A+S, 4A+S)        tstarts  (exclusive scan of counts*(counts-1)) == int2 offset
//   [4A+S, 4A+S+n_bond) sorted_bond (kept bond ids grouped by central atom)
// ---------------------------------------------------------------------------

#define MAXC 256  // per-atom LDS segment capacity (fallback to global beyond)

__global__ void k_init(int* __restrict__ p, int n) {
    int i = blockIdx.x * blockDim.x + threadIdx.x;
    if (i < n) p[i] = 0;
}

__global__ void k_count(const int* __restrict__ bai, const float* __restrict__ blen,
                        const float* __restrict__ cutp, int* __restrict__ counts,
                        int n_bond) {
    int b = blockIdx.x * blockDim.x + threadIdx.x;
    if (b >= n_bond) return;
    if (blen[b] <= *cutp) atomicAdd(&counts[bai[2 * b]], 1);
}

// Single-block dual exclusive scan over A elements:
//   starts[i]  = sum_{k<i} counts[k]
//   tstarts[i] = sum_{k<i} counts[k]*(counts[k]-1)   (ordered pairs == int2 units)
__global__ __launch_bounds__(1024) void k_scan(const int* __restrict__ counts,
                                               int* __restrict__ starts,
                                               int* __restrict__ tstarts, int A) {
    const int T = 1024;
    __shared__ int sc[T];
    __shared__ int st[T];
    int tid = threadIdx.x;
    int chunk = (A + T - 1) / T;
    int lo = tid * chunk;
    int hi = lo + chunk;
    if (hi > A) hi = A;

    int pc = 0, pt = 0;
    for (int i = lo; i < hi; ++i) {
        int c = counts[i];
        pc += c;
        pt += c * (c - 1);
    }
    sc[tid] = pc;
    st[tid] = pt;
    __syncthreads();
    for (int off = 1; off < T; off <<= 1) {
        int vc = 0, vt = 0;
        if (tid >= off) { vc = sc[tid - off]; vt = st[tid - off]; }
        __syncthreads();
        sc[tid] += vc;
        st[tid] += vt;
        __syncthreads();
    }
    int rc = sc[tid] - pc;
    int rt = st[tid] - pt;
    for (int i = lo; i < hi; ++i) {
        int c = counts[i];
        starts[i] = rc;
        tstarts[i] = rt;
        rc += c;
        rt += c * (c - 1);
    }
}

__global__ void k_scatter(const int* __restrict__ bai, const float* __restrict__ blen,
                          const float* __restrict__ cutp, const int* __restrict__ counts,
                          const int* __restrict__ starts, int* __restrict__ cursor,
                          int* __restrict__ sorted_bond, int* __restrict__ out_ij,
                          int n_bond) {
    int b = blockIdx.x * blockDim.x + threadIdx.x;
    if (b >= n_bond) return;
    if (blen[b] <= *cutp) {
        int c = bai[2 * b];
        int cnt = counts[c];
        out_ij[b] = cnt > 1 ? cnt - 1 : 0;
        int r = atomicAdd(&cursor[c], 1);
        sorted_bond[starts[c] + r] = b;
    } else {
        out_ij[b] = 0;
    }
}

// One wave (block of 64) per atom. Lane 0: bookkeeping + insertion sort of
// the segment (restores deterministic ascending bond-id order after the
// nondeterministic atomic scatter). All lanes then emit combination pairs
// as coalesced int2 stores: forward block [bi,bj], then flipped block [bj,bi].
__global__ __launch_bounds__(64) void k_pairs(
        const int* __restrict__ counts, const int* __restrict__ starts,
        const int* __restrict__ tstarts, int* __restrict__ sorted_bond,
        const int* __restrict__ n_atoms, int n_struct,
        int* __restrict__ ns_acc, int* __restrict__ out_ti,
        int2* __restrict__ out_bi, int A) {
    int a = blockIdx.x;
    if (a >= A) return;
    int lane = threadIdx.x;

    __shared__ int seg[MAXC];

    int c = counts[a];
    int ti = c * (c - 1);

    if (lane == 0) {
        out_ti[a] = ti;
        if (ti > 0) {
            int cum = 0, s = 0;
            for (s = 0; s < n_struct; ++s) {
                cum += n_atoms[s];
                if (a < cum) break;
            }
            atomicAdd(&ns_acc[s], ti);
        }
    }
    if (c < 2) return;

    int st0 = starts[a];
    bool use_lds = (c <= MAXC);

    if (use_lds) {
        for (int i = lane; i < c; i += 64) seg[i] = sorted_bond[st0 + i];
    }
    __syncthreads();
    if (lane == 0) {
        int* sp = use_lds ? seg : &sorted_bond[st0];
        for (int i = 1; i < c; ++i) {
            int v = sp[i];
            int j = i - 1;
            while (j >= 0 && sp[j] > v) { sp[j + 1] = sp[j]; --j; }
            sp[j + 1] = v;
        }
    }
    __syncthreads();

    const int* sp = use_lds ? seg : &sorted_bond[st0];
    int P = ti >> 1;                       // number of (i<j) combos
    int2* outp = out_bi + tstarts[a];      // atom block: 2P int2 (P fwd + P flip)
    for (int p = lane; p < P; p += 64) {
        int i = 0, rem = p;
        while (rem >= c - 1 - i) { rem -= c - 1 - i; ++i; }
        int j = i + 1 + rem;
        int bi = sp[i], bj = sp[j];
        outp[p]     = make_int2(bi, bj);
        outp[P + p] = make_int2(bj, bi);
    }
}

__global__ void k_copy_ns(const int* __restrict__ ns_acc, int* __restrict__ out_ns, int S) {
    int i = blockIdx.x * blockDim.x + threadIdx.x;
    if (i < S) out_ns[i] = ns_acc[i];
}

extern "C" void kernel_launch(void* const* d_in, const int* in_sizes, int n_in,
                              void* d_out, int out_size, void* d_ws, size_t ws_size,
                              hipStream_t stream) {
    const int* bai      = (const int*)d_in[0];    // [n_bond,2] int32
    const float* blen   = (const float*)d_in[1];  // [n_bond] f32
    const int* n_atoms  = (const int*)d_in[2];    // [S] int32
    // d_in[3] = atomic_number (unused)
    const float* cutp   = (const float*)d_in[4];  // scalar f32

    int n_bond = in_sizes[1];
    int S      = in_sizes[2];
    int A      = in_sizes[3];

    int n_tr2 = out_size - n_bond - A - S;  // 2 * n_triple

    int* out     = (int*)d_out;
    int2* out_bi = (int2*)out;          // [n_triple] pairs
    int* out_ij  = out + n_tr2;         // [n_bond]
    int* out_ti  = out_ij + n_bond;     // [A]
    int* out_ns  = out_ti + A;          // [S]

    int* ws          = (int*)d_ws;
    int* counts      = ws;
    int* cursor      = ws + A;
    int* ns_acc      = ws + 2 * A;
    int* starts      = ws + 2 * A + S;
    int* tstarts     = ws + 3 * A + S;
    int* sorted_bond = ws + 4 * A + S;

    int zn = 2 * A + S;  // counts + cursor + ns_acc contiguous
    k_init<<<(zn + 255) / 256, 256, 0, stream>>>(ws, zn);
    k_count<<<(n_bond + 255) / 256, 256, 0, stream>>>(bai, blen, cutp, counts, n_bond);
    k_scan<<<1, 1024, 0, stream>>>(counts, starts, tstarts, A);
    k_scatter<<<(n_bond + 255) / 256, 256, 0, stream>>>(bai, blen, cutp, counts, starts,
                                                        cursor, sorted_bond, out_ij, n_bond);
    k_pairs<<<A, 64, 0, stream>>>(counts, starts, tstarts, sorted_bond,
                                  n_atoms, S, ns_acc, out_ti, out_bi, A);
    k_copy_ns<<<1, 64, 0, stream>>>(ns_acc, out_ns, S);
}

// Round 4
// 102.545 us; speedup vs baseline: 3.5300x; 3.0085x over previous
//
#include <hip/hip_runtime.h>

// ---------------------------------------------------------------------------
// threebody indices (MatterSim). All outputs int32.
// ws layout (int32):
//   [0, A)                counts
//   [A, 2A)               cursor
//   [2A, 3A)              starts   (exclusive scan of counts)
//   [3A, 4A+1)            tstarts  (exclusive scan of counts*(counts-1), +total at [A])
//   [4A+1, 4A+1+n_bond)   sorted_bond (kept bond ids grouped by central atom)
// ---------------------------------------------------------------------------

#define MAXC 256  // per-atom LDS segment capacity (fallback to global beyond)

__global__ void k_init(int* __restrict__ p, int n) {
    int i = blockIdx.x * blockDim.x + threadIdx.x;
    if (i < n) p[i] = 0;
}

__global__ void k_count(const int* __restrict__ bai, const float* __restrict__ blen,
                        const float* __restrict__ cutp, int* __restrict__ counts,
                        int n_bond) {
    int b = blockIdx.x * blockDim.x + threadIdx.x;
    if (b >= n_bond) return;
    if (blen[b] <= *cutp) atomicAdd(&counts[bai[2 * b]], 1);
}

// Single-block dual exclusive scan over A elements:
//   starts[i]  = sum_{k<i} counts[k]
//   tstarts[i] = sum_{k<i} counts[k]*(counts[k]-1)   (ordered pairs == int2 units)
//   tstarts[A] = grand total
__global__ __launch_bounds__(1024) void k_scan(const int* __restrict__ counts,
                                               int* __restrict__ starts,
                                               int* __restrict__ tstarts, int A) {
    const int T = 1024;
    __shared__ int sc[T];
    __shared__ int st[T];
    int tid = threadIdx.x;
    int chunk = (A + T - 1) / T;
    int lo = tid * chunk;
    int hi = lo + chunk;
    if (hi > A) hi = A;

    int pc = 0, pt = 0;
    for (int i = lo; i < hi; ++i) {
        int c = counts[i];
        pc += c;
        pt += c * (c - 1);
    }
    sc[tid] = pc;
    st[tid] = pt;
    __syncthreads();
    for (int off = 1; off < T; off <<= 1) {
        int vc = 0, vt = 0;
        if (tid >= off) { vc = sc[tid - off]; vt = st[tid - off]; }
        __syncthreads();
        sc[tid] += vc;
        st[tid] += vt;
        __syncthreads();
    }
    int rc = sc[tid] - pc;
    int rt = st[tid] - pt;
    for (int i = lo; i < hi; ++i) {
        int c = counts[i];
        starts[i] = rc;
        tstarts[i] = rt;
        rc += c;
        rt += c * (c - 1);
    }
    if (tid == T - 1) tstarts[A] = rt;  // grand total of c*(c-1)
}

__global__ void k_scatter(const int* __restrict__ bai, const float* __restrict__ blen,
                          const float* __restrict__ cutp, const int* __restrict__ counts,
                          const int* __restrict__ starts, int* __restrict__ cursor,
                          int* __restrict__ sorted_bond, int* __restrict__ out_ij,
                          int n_bond) {
    int b = blockIdx.x * blockDim.x + threadIdx.x;
    if (b >= n_bond) return;
    if (blen[b] <= *cutp) {
        int c = bai[2 * b];
        int cnt = counts[c];
        out_ij[b] = cnt > 1 ? cnt - 1 : 0;
        int r = atomicAdd(&cursor[c], 1);
        sorted_bond[starts[c] + r] = b;
    } else {
        out_ij[b] = 0;
    }
}

// One wave (block of 64) per atom. Lane 0: n_triple_i + insertion sort of the
// segment (restores deterministic ascending bond-id order after the
// nondeterministic atomic scatter). All lanes then emit combination pairs
// as coalesced int2 stores: forward block [bi,bj], then flipped block [bj,bi].
__global__ __launch_bounds__(64) void k_pairs(
        const int* __restrict__ counts, const int* __restrict__ starts,
        const int* __restrict__ tstarts, int* __restrict__ sorted_bond,
        int* __restrict__ out_ti, int2* __restrict__ out_bi, int A) {
    int a = blockIdx.x;
    if (a >= A) return;
    int lane = threadIdx.x;

    __shared__ int seg[MAXC];

    int c = counts[a];
    int ti = c * (c - 1);

    if (lane == 0) out_ti[a] = ti;
    if (c < 2) return;

    int st0 = starts[a];
    bool use_lds = (c <= MAXC);

    if (use_lds) {
        for (int i = lane; i < c; i += 64) seg[i] = sorted_bond[st0 + i];
    }
    __syncthreads();
    if (lane == 0) {
        int* sp = use_lds ? seg : &sorted_bond[st0];
        for (int i = 1; i < c; ++i) {
            int v = sp[i];
            int j = i - 1;
            while (j >= 0 && sp[j] > v) { sp[j + 1] = sp[j]; --j; }
            sp[j + 1] = v;
        }
    }
    __syncthreads();

    const int* sp = use_lds ? seg : &sorted_bond[st0];
    int P = ti >> 1;                       // number of (i<j) combos
    int2* outp = out_bi + tstarts[a];      // atom block: 2P int2 (P fwd + P flip)
    for (int p = lane; p < P; p += 64) {
        int i = 0, rem = p;
        while (rem >= c - 1 - i) { rem -= c - 1 - i; ++i; }
        int j = i + 1 + rem;
        int bi = sp[i], bj = sp[j];
        outp[p]     = make_int2(bi, bj);
        outp[P + p] = make_int2(bj, bi);
    }
}

// n_triple_s[s] = tstarts[bound[s+1]] - tstarts[bound[s]]  (no atomics)
__global__ void k_ns(const int* __restrict__ tstarts, const int* __restrict__ n_atoms,
                     int* __restrict__ out_ns, int S) {
    int s = threadIdx.x;
    if (s >= S) return;
    int lo = 0;
    for (int k = 0; k < s; ++k) lo += n_atoms[k];
    int hi = lo + n_atoms[s];
    out_ns[s] = tstarts[hi] - tstarts[lo];
}

extern "C" void kernel_launch(void* const* d_in, const int* in_sizes, int n_in,
                              void* d_out, int out_size, void* d_ws, size_t ws_size,
                              hipStream_t stream) {
    const int* bai      = (const int*)d_in[0];    // [n_bond,2] int32
    const float* blen   = (const float*)d_in[1];  // [n_bond] f32
    const int* n_atoms  = (const int*)d_in[2];    // [S] int32
    // d_in[3] = atomic_number (unused)
    const float* cutp   = (const float*)d_in[4];  // scalar f32

    int n_bond = in_sizes[1];
    int S      = in_sizes[2];
    int A      = in_sizes[3];

    int n_tr2 = out_size - n_bond - A - S;  // 2 * n_triple

    int* out     = (int*)d_out;
    int2* out_bi = (int2*)out;          // [n_triple] pairs
    int* out_ij  = out + n_tr2;         // [n_bond]
    int* out_ti  = out_ij + n_bond;     // [A]
    int* out_ns  = out_ti + A;          // [S]

    int* ws          = (int*)d_ws;
    int* counts      = ws;
    int* cursor      = ws + A;
    int* starts      = ws + 2 * A;
    int* tstarts     = ws + 3 * A;          // size A+1
    int* sorted_bond = ws + 4 * A + 1;

    int zn = 2 * A;  // counts + cursor contiguous
    k_init<<<(zn + 255) / 256, 256, 0, stream>>>(ws, zn);
    k_count<<<(n_bond + 255) / 256, 256, 0, stream>>>(bai, blen, cutp, counts, n_bond);
    k_scan<<<1, 1024, 0, stream>>>(counts, starts, tstarts, A);
    k_scatter<<<(n_bond + 255) / 256, 256, 0, stream>>>(bai, blen, cutp, counts, starts,
                                                        cursor, sorted_bond, out_ij, n_bond);
    k_pairs<<<A, 64, 0, stream>>>(counts, starts, tstarts, sorted_bond,
                                  out_ti, out_bi, A);
    k_ns<<<1, 64, 0, stream>>>(tstarts, n_atoms, out_ns, S);
}

// Round 5
// 100.272 us; speedup vs baseline: 3.6100x; 1.0227x over previous
//
#include <hip/hip_runtime.h>

// ---------------------------------------------------------------------------
// threebody indices (MatterSim). All outputs int32.
// ws layout (int32):
//   [0, A)            counts
//   [A, 2A)           cursor
//   [2A, 3A)          starts   (exclusive scan of counts)
//   [3A, 4A+1)        tstarts  (exclusive scan of c*(c-1); [A] = grand total)
//   [4A+4, 8A+4)      meta     (int4 per atom: {c, start, tstart, 0}, 16B aligned)
//   [8A+4, 8A+4+n_bond) sorted_bond (kept bond ids grouped by central atom)
// ---------------------------------------------------------------------------

#define WPB 4  // waves (atoms) per block in k_pairs

__global__ void k_count(const int2* __restrict__ bai, const float* __restrict__ blen,
                        const float* __restrict__ cutp, int* __restrict__ counts,
                        int n_bond) {
    int b = blockIdx.x * blockDim.x + threadIdx.x;
    if (b >= n_bond) return;
    if (blen[b] <= *cutp) atomicAdd(&counts[bai[b].x], 1);
}

// Single-block dual exclusive scan over A elements. Also emits packed meta,
// out_ti (= c*(c-1)), and per-structure triple sums (scan differences).
__global__ __launch_bounds__(1024) void k_scan(const int* __restrict__ counts,
                                               int* __restrict__ starts,
                                               int* __restrict__ tstarts,
                                               int4* __restrict__ meta,
                                               int* __restrict__ out_ti,
                                               const int* __restrict__ n_atoms,
                                               int* __restrict__ out_ns,
                                               int S, int A) {
    const int T = 1024;
    __shared__ int sc[T];
    __shared__ int st[T];
    int tid = threadIdx.x;
    int chunk = (A + T - 1) / T;
    int lo = tid * chunk;
    int hi = lo + chunk;
    if (hi > A) hi = A;

    int pc = 0, pt = 0;
    for (int i = lo; i < hi; ++i) {
        int c = counts[i];
        pc += c;
        pt += c * (c - 1);
    }
    sc[tid] = pc;
    st[tid] = pt;
    __syncthreads();
    for (int off = 1; off < T; off <<= 1) {
        int vc = 0, vt = 0;
        if (tid >= off) { vc = sc[tid - off]; vt = st[tid - off]; }
        __syncthreads();
        sc[tid] += vc;
        st[tid] += vt;
        __syncthreads();
    }
    int rc = sc[tid] - pc;   // exclusive base for this thread's chunk
    int rt = st[tid] - pt;
    for (int i = lo; i < hi; ++i) {
        int c = counts[i];
        starts[i] = rc;
        tstarts[i] = rt;
        meta[i] = make_int4(c, rc, rt, 0);
        out_ti[i] = c * (c - 1);
        rc += c;
        rt += c * (c - 1);
    }
    if (tid == T - 1) tstarts[A] = rt;  // grand total
    __syncthreads();
    if (tid < S) {
        int blo = 0;
        for (int k = 0; k < tid; ++k) blo += n_atoms[k];
        int bhi = blo + n_atoms[tid];
        out_ns[tid] = tstarts[bhi] - tstarts[blo];
    }
}

__global__ void k_scatter(const int2* __restrict__ bai, const float* __restrict__ blen,
                          const float* __restrict__ cutp, const int* __restrict__ counts,
                          const int* __restrict__ starts, int* __restrict__ cursor,
                          int* __restrict__ sorted_bond, int* __restrict__ out_ij,
                          int n_bond) {
    int b = blockIdx.x * blockDim.x + threadIdx.x;
    if (b >= n_bond) return;
    if (blen[b] <= *cutp) {
        int c = bai[b].x;
        int cnt = counts[c];
        out_ij[b] = cnt > 1 ? cnt - 1 : 0;
        int r = atomicAdd(&cursor[c], 1);
        sorted_bond[starts[c] + r] = b;
    } else {
        out_ij[b] = 0;
    }
}

// One wave per atom, WPB atoms per 256-thread block, no LDS, no block barriers.
// Sort: wave-parallel rank sort (shfl compare loop, c <= 64; bond ids unique)
// then ds_permute scatters values into sorted lane order. Emission: all lanes
// write coalesced int2 pairs: forward block [bi,bj], then flipped [bj,bi].
__global__ __launch_bounds__(256) void k_pairs(const int4* __restrict__ meta,
                                               int* __restrict__ sorted_bond,
                                               int2* __restrict__ out_bi, int A) {
    int wv = threadIdx.x >> 6;
    int lane = threadIdx.x & 63;
    int a = blockIdx.x * WPB + wv;
    if (a >= A) return;

    int4 m = meta[a];
    int c = m.x;
    if (c < 2) return;
    int st0 = m.y;
    int P = (c * (c - 1)) >> 1;        // (i<j) combos
    int2* outp = out_bi + m.z;         // atom block: 2P int2

    if (c <= 64) {
        int v = (lane < c) ? sorted_bond[st0 + lane] : 0x7fffffff;
        int rank = 0;
        for (int j = 0; j < c; ++j) {
            int vj = __shfl(v, j, 64);
            rank += (vj < v) ? 1 : 0;
        }
        // lanes >= c all land on lane c (if c<64): harmless, never read.
        int sv = __builtin_amdgcn_ds_permute(rank << 2, v);

        int niter = (P + 63) >> 6;
        for (int it = 0; it < niter; ++it) {
            int p = (it << 6) + lane;
            bool act = p < P;
            int pp = act ? p : 0;
            int i = 0, rem = pp;
            while (rem >= c - 1 - i) { rem -= c - 1 - i; ++i; }
            int j = i + 1 + rem;
            int bi = __shfl(sv, i, 64);   // all lanes active: shfl well-defined
            int bj = __shfl(sv, j, 64);
            if (act) {
                outp[p]     = make_int2(bi, bj);
                outp[P + p] = make_int2(bj, bi);
            }
        }
    } else if (lane == 0) {
        // rare fallback (c > 64): serial sort + serial emit, single lane,
        // all through its own global loads/stores (no cross-lane visibility).
        for (int i = 1; i < c; ++i) {
            int v = sorted_bond[st0 + i];
            int j = i - 1;
            while (j >= 0 && sorted_bond[st0 + j] > v) {
                sorted_bond[st0 + j + 1] = sorted_bond[st0 + j];
                --j;
            }
            sorted_bond[st0 + j + 1] = v;
        }
        int p = 0;
        for (int i = 0; i < c; ++i) {
            int bi = sorted_bond[st0 + i];
            for (int j = i + 1; j < c; ++j) {
                int bj = sorted_bond[st0 + j];
                outp[p]     = make_int2(bi, bj);
                outp[P + p] = make_int2(bj, bi);
                ++p;
            }
        }
    }
}

extern "C" void kernel_launch(void* const* d_in, const int* in_sizes, int n_in,
                              void* d_out, int out_size, void* d_ws, size_t ws_size,
                              hipStream_t stream) {
    const int2* bai     = (const int2*)d_in[0];   // [n_bond,2] int32
    const float* blen   = (const float*)d_in[1];  // [n_bond] f32
    const int* n_atoms  = (const int*)d_in[2];    // [S] int32
    // d_in[3] = atomic_number (unused)
    const float* cutp   = (const float*)d_in[4];  // scalar f32

    int n_bond = in_sizes[1];
    int S      = in_sizes[2];
    int A      = in_sizes[3];

    int n_tr2 = out_size - n_bond - A - S;  // 2 * n_triple

    int* out     = (int*)d_out;
    int2* out_bi = (int2*)out;          // [n_triple] pairs
    int* out_ij  = out + n_tr2;         // [n_bond]
    int* out_ti  = out_ij + n_bond;     // [A]
    int* out_ns  = out_ti + A;          // [S]

    int* ws          = (int*)d_ws;
    int* counts      = ws;
    int* cursor      = ws + A;
    int* starts      = ws + 2 * A;
    int* tstarts     = ws + 3 * A;                  // A+1, padded to 4A+4
    int4* meta       = (int4*)(ws + 4 * A + 4);     // 16B aligned
    int* sorted_bond = ws + 8 * A + 4;

    hipMemsetAsync(ws, 0, (size_t)(2 * A) * sizeof(int), stream);  // counts+cursor
    k_count<<<(n_bond + 255) / 256, 256, 0, stream>>>(bai, blen, cutp, counts, n_bond);
    k_scan<<<1, 1024, 0, stream>>>(counts, starts, tstarts, meta, out_ti,
                                   n_atoms, out_ns, S, A);
    k_scatter<<<(n_bond + 255) / 256, 256, 0, stream>>>(bai, blen, cutp, counts, starts,
                                                        cursor, sorted_bond, out_ij, n_bond);
    k_pairs<<<(A + WPB - 1) / WPB, WPB * 64, 0, stream>>>(meta, sorted_bond, out_bi, A);
}

// Round 6
// 51.941 us; speedup vs baseline: 6.9692x; 1.9305x over previous
//
#include <hip/hip_runtime.h>

// ---------------------------------------------------------------------------
// threebody indices (MatterSim). All outputs int32.
// ws layout (int32):
//   [0, A)              counts
//   [A, 2A)             cursor
//   [2A, 3A)            starts   (exclusive scan of counts)
//   [3A, 4A+1)          tstarts  (exclusive scan of c*(c-1); [A] = grand total)
//   [4A+4, 8A+4)        meta     (int4 per atom: {c, start, tstart, 0})
//   [8A+4, 8A+4+n_bond) sorted_bond (kept bond ids grouped by central atom)
//   [8A+4+n_bond, ...)  partials (int2 per scan block)
// ---------------------------------------------------------------------------

#define WPB 4    // waves (atoms) per block in k_pairs
#define BLK 256  // scan block size

__global__ void k_count(const int2* __restrict__ bai, const float* __restrict__ blen,
                        const float* __restrict__ cutp, int* __restrict__ counts,
                        int n_bond) {
    int b = blockIdx.x * blockDim.x + threadIdx.x;
    if (b >= n_bond) return;
    if (blen[b] <= *cutp) atomicAdd(&counts[bai[b].x], 1);
}

// Per-block reduce of (c, c*(c-1)) -> partials[block]
__global__ __launch_bounds__(BLK) void k_part(const int* __restrict__ counts,
                                              int2* __restrict__ partials, int A) {
    int i = blockIdx.x * BLK + threadIdx.x;
    int c = (i < A) ? counts[i] : 0;
    int t = c * (c - 1);
    int lane = threadIdx.x & 63, wv = threadIdx.x >> 6;
    for (int off = 32; off; off >>= 1) {
        c += __shfl_down(c, off, 64);
        t += __shfl_down(t, off, 64);
    }
    __shared__ int sc[BLK / 64], st[BLK / 64];
    if (lane == 0) { sc[wv] = c; st[wv] = t; }
    __syncthreads();
    if (threadIdx.x == 0) {
        int tc = 0, tt = 0;
        for (int w = 0; w < BLK / 64; ++w) { tc += sc[w]; tt += st[w]; }
        partials[blockIdx.x] = make_int2(tc, tt);
    }
}

// Single-block exclusive scan of NB partials (in place); grand total -> *totp
__global__ __launch_bounds__(1024) void k_mid(int2* __restrict__ partials, int NB,
                                              int* __restrict__ totp) {
    const int T = 1024;
    __shared__ int sc[T], st[T];
    int tid = threadIdx.x;
    int chunk = (NB + T - 1) / T;
    int lo = tid * chunk, hi = lo + chunk;
    if (hi > NB) hi = NB;
    int pc = 0, pt = 0;
    for (int i = lo; i < hi; ++i) { pc += partials[i].x; pt += partials[i].y; }
    sc[tid] = pc; st[tid] = pt;
    __syncthreads();
    for (int off = 1; off < T; off <<= 1) {
        int vc = 0, vt = 0;
        if (tid >= off) { vc = sc[tid - off]; vt = st[tid - off]; }
        __syncthreads();
        sc[tid] += vc; st[tid] += vt;
        __syncthreads();
    }
    int rc = sc[tid] - pc, rt = st[tid] - pt;
    for (int i = lo; i < hi; ++i) {
        int2 v = partials[i];
        partials[i] = make_int2(rc, rt);
        rc += v.x; rt += v.y;
    }
    if (tid == T - 1) *totp = rt;  // grand total of c*(c-1)
}

// Block-level scan + block offset; writes starts/tstarts/meta/out_ti coalesced.
__global__ __launch_bounds__(BLK) void k_final(const int* __restrict__ counts,
                                               const int2* __restrict__ partials,
                                               int* __restrict__ starts,
                                               int* __restrict__ tstarts,
                                               int4* __restrict__ meta,
                                               int* __restrict__ out_ti, int A) {
    int i = blockIdx.x * BLK + threadIdx.x;
    int c = (i < A) ? counts[i] : 0;
    int t = c * (c - 1);
    int lane = threadIdx.x & 63, wv = threadIdx.x >> 6;
    int ic = c, it = t;  // inclusive wave scan
    for (int off = 1; off < 64; off <<= 1) {
        int nc = __shfl_up(ic, off, 64), nt = __shfl_up(it, off, 64);
        if (lane >= off) { ic += nc; it += nt; }
    }
    __shared__ int wc[BLK / 64], wt[BLK / 64];
    if (lane == 63) { wc[wv] = ic; wt[wv] = it; }
    __syncthreads();
    int bc = 0, bt = 0;
    for (int w = 0; w < wv; ++w) { bc += wc[w]; bt += wt[w]; }
    int2 bo = partials[blockIdx.x];
    int sx = bo.x + bc + ic - c;   // exclusive
    int tx = bo.y + bt + it - t;
    if (i < A) {
        starts[i] = sx;
        tstarts[i] = tx;
        meta[i] = make_int4(c, sx, tx, 0);
        out_ti[i] = t;
    }
}

__global__ void k_scatter(const int2* __restrict__ bai, const float* __restrict__ blen,
                          const float* __restrict__ cutp, const int* __restrict__ counts,
                          const int* __restrict__ starts, int* __restrict__ cursor,
                          int* __restrict__ sorted_bond, int* __restrict__ out_ij,
                          int n_bond) {
    int b = blockIdx.x * blockDim.x + threadIdx.x;
    if (b >= n_bond) return;
    if (blen[b] <= *cutp) {
        int c = bai[b].x;
        int cnt = counts[c];
        out_ij[b] = cnt > 1 ? cnt - 1 : 0;
        int r = atomicAdd(&cursor[c], 1);
        sorted_bond[starts[c] + r] = b;
    } else {
        out_ij[b] = 0;
    }
}

// One wave per atom, WPB atoms per block, no LDS/barriers. Wave-parallel rank
// sort (bond ids unique, c<=64 path) then coalesced int2 pair emission.
// Block 0 also writes out_ns from tstarts differences (tstarts complete here).
__global__ __launch_bounds__(WPB * 64) void k_pairs(
        const int4* __restrict__ meta, int* __restrict__ sorted_bond,
        int2* __restrict__ out_bi, const int* __restrict__ tstarts,
        const int* __restrict__ n_atoms, int* __restrict__ out_ns,
        int S, int A) {
    if (blockIdx.x == 0 && threadIdx.x < S) {
        int s = threadIdx.x;
        int blo = 0;
        for (int k = 0; k < s; ++k) blo += n_atoms[k];
        int bhi = blo + n_atoms[s];
        out_ns[s] = tstarts[bhi] - tstarts[blo];
    }

    int wv = threadIdx.x >> 6;
    int lane = threadIdx.x & 63;
    int a = blockIdx.x * WPB + wv;
    if (a >= A) return;

    int4 m = meta[a];
    int c = m.x;
    if (c < 2) return;
    int st0 = m.y;
    int P = (c * (c - 1)) >> 1;        // (i<j) combos
    int2* outp = out_bi + m.z;         // atom block: 2P int2

    if (c <= 64) {
        int v = (lane < c) ? sorted_bond[st0 + lane] : 0x7fffffff;
        int rank = 0;
        for (int j = 0; j < c; ++j) {
            int vj = __shfl(v, j, 64);
            rank += (vj < v) ? 1 : 0;
        }
        int sv = __builtin_amdgcn_ds_permute(rank << 2, v);

        int niter = (P + 63) >> 6;
        for (int it = 0; it < niter; ++it) {
            int p = (it << 6) + lane;
            bool act = p < P;
            int pp = act ? p : 0;
            int i = 0, rem = pp;
            while (rem >= c - 1 - i) { rem -= c - 1 - i; ++i; }
            int j = i + 1 + rem;
            int bi = __shfl(sv, i, 64);
            int bj = __shfl(sv, j, 64);
            if (act) {
                outp[p]     = make_int2(bi, bj);
                outp[P + p] = make_int2(bj, bi);
            }
        }
    } else if (lane == 0) {
        for (int i = 1; i < c; ++i) {
            int v = sorted_bond[st0 + i];
            int j = i - 1;
            while (j >= 0 && sorted_bond[st0 + j] > v) {
                sorted_bond[st0 + j + 1] = sorted_bond[st0 + j];
                --j;
            }
            sorted_bond[st0 + j + 1] = v;
        }
        int p = 0;
        for (int i = 0; i < c; ++i) {
            int bi = sorted_bond[st0 + i];
            for (int j = i + 1; j < c; ++j) {
                int bj = sorted_bond[st0 + j];
                outp[p]     = make_int2(bi, bj);
                outp[P + p] = make_int2(bj, bi);
                ++p;
            }
        }
    }
}

extern "C" void kernel_launch(void* const* d_in, const int* in_sizes, int n_in,
                              void* d_out, int out_size, void* d_ws, size_t ws_size,
                              hipStream_t stream) {
    const int2* bai     = (const int2*)d_in[0];   // [n_bond,2] int32
    const float* blen   = (const float*)d_in[1];  // [n_bond] f32
    const int* n_atoms  = (const int*)d_in[2];    // [S] int32
    // d_in[3] = atomic_number (unused)
    const float* cutp   = (const float*)d_in[4];  // scalar f32

    int n_bond = in_sizes[1];
    int S      = in_sizes[2];
    int A      = in_sizes[3];

    int n_tr2 = out_size - n_bond - A - S;  // 2 * n_triple

    int* out     = (int*)d_out;
    int2* out_bi = (int2*)out;          // [n_triple] pairs
    int* out_ij  = out + n_tr2;         // [n_bond]
    int* out_ti  = out_ij + n_bond;     // [A]
    int* out_ns  = out_ti + A;          // [S]

    int* ws          = (int*)d_ws;
    int* counts      = ws;
    int* cursor      = ws + A;
    int* starts      = ws + 2 * A;
    int* tstarts     = ws + 3 * A;                  // A+1, padded to 4A+4
    int4* meta       = (int4*)(ws + 4 * A + 4);     // 16B aligned
    int* sorted_bond = ws + 8 * A + 4;
    int2* partials   = (int2*)(ws + 8 * A + 4 + n_bond);

    int NB = (A + BLK - 1) / BLK;

    hipMemsetAsync(ws, 0, (size_t)(2 * A) * sizeof(int), stream);  // counts+cursor
    k_count<<<(n_bond + 255) / 256, 256, 0, stream>>>(bai, blen, cutp, counts, n_bond);
    k_part<<<NB, BLK, 0, stream>>>(counts, partials, A);
    k_mid<<<1, 1024, 0, stream>>>(partials, NB, &tstarts[A]);
    k_final<<<NB, BLK, 0, stream>>>(counts, partials, starts, tstarts, meta, out_ti, A);
    k_scatter<<<(n_bond + 255) / 256, 256, 0, stream>>>(bai, blen, cutp, counts, starts,
                                                        cursor, sorted_bond, out_ij, n_bond);
    k_pairs<<<(A + WPB - 1) / WPB, WPB * 64, 0, stream>>>(meta, sorted_bond, out_bi,
                                                          tstarts, n_atoms, out_ns, S, A);
}

// Round 7
// 51.412 us; speedup vs baseline: 7.0407x; 1.0103x over previous
//
#include <hip/hip_runtime.h>

// ---------------------------------------------------------------------------
// threebody indices (MatterSim). All outputs int32.
// ws layout (int32):
//   [0, A)              counts
//   [A, 2A)             cursor   (init to starts[] by k_final)
//   [2A, 3A)            starts   (exclusive scan of counts)
//   [3A, 4A+1)          tstarts  (exclusive scan of c*(c-1); [A] = grand total)
//   [4A+4, 8A+4)        meta     (int4 per atom: {c, start, tstart, 0})
//   [8A+4, 8A+4+n_bond) sorted_bond (kept bond ids grouped by central atom)
//   [8A+4+n_bond, ...)  partials (int2 per scan block)
// ---------------------------------------------------------------------------

#define WPB 4    // waves (atoms) per block in k_pairs
#define BLK 256  // scan block size

__global__ void k_init(int* __restrict__ p, int n) {
    int i = blockIdx.x * blockDim.x + threadIdx.x;
    if (i < n) p[i] = 0;
}

__global__ void k_count(const int2* __restrict__ bai, const float* __restrict__ blen,
                        const float* __restrict__ cutp, int* __restrict__ counts,
                        int n_bond) {
    int b = blockIdx.x * blockDim.x + threadIdx.x;
    if (b >= n_bond) return;
    if (blen[b] <= *cutp) atomicAdd(&counts[bai[b].x], 1);
}

// Per-block reduce of (c, c*(c-1)) -> partials[block]
__global__ __launch_bounds__(BLK) void k_part(const int* __restrict__ counts,
                                              int2* __restrict__ partials, int A) {
    int i = blockIdx.x * BLK + threadIdx.x;
    int c = (i < A) ? counts[i] : 0;
    int t = c * (c - 1);
    int lane = threadIdx.x & 63, wv = threadIdx.x >> 6;
    for (int off = 32; off; off >>= 1) {
        c += __shfl_down(c, off, 64);
        t += __shfl_down(t, off, 64);
    }
    __shared__ int sc[BLK / 64], st[BLK / 64];
    if (lane == 0) { sc[wv] = c; st[wv] = t; }
    __syncthreads();
    if (threadIdx.x == 0) {
        int tc = 0, tt = 0;
        for (int w = 0; w < BLK / 64; ++w) { tc += sc[w]; tt += st[w]; }
        partials[blockIdx.x] = make_int2(tc, tt);
    }
}

// Single-block exclusive scan of NB partials (in place); grand total -> *totp
__global__ __launch_bounds__(1024) void k_mid(int2* __restrict__ partials, int NB,
                                              int* __restrict__ totp) {
    const int T = 1024;
    __shared__ int sc[T], st[T];
    int tid = threadIdx.x;
    int chunk = (NB + T - 1) / T;
    int lo = tid * chunk, hi = lo + chunk;
    if (hi > NB) hi = NB;
    int pc = 0, pt = 0;
    for (int i = lo; i < hi; ++i) { pc += partials[i].x; pt += partials[i].y; }
    sc[tid] = pc; st[tid] = pt;
    __syncthreads();
    for (int off = 1; off < T; off <<= 1) {
        int vc = 0, vt = 0;
        if (tid >= off) { vc = sc[tid - off]; vt = st[tid - off]; }
        __syncthreads();
        sc[tid] += vc; st[tid] += vt;
        __syncthreads();
    }
    int rc = sc[tid] - pc, rt = st[tid] - pt;
    for (int i = lo; i < hi; ++i) {
        int2 v = partials[i];
        partials[i] = make_int2(rc, rt);
        rc += v.x; rt += v.y;
    }
    if (tid == T - 1) *totp = rt;  // grand total of c*(c-1)
}

// Block-level scan + block offset; writes starts/tstarts/meta/out_ti/cursor
// (cursor initialized to the segment start -> no memset needed).
__global__ __launch_bounds__(BLK) void k_final(const int* __restrict__ counts,
                                               const int2* __restrict__ partials,
                                               int* __restrict__ starts,
                                               int* __restrict__ tstarts,
                                               int4* __restrict__ meta,
                                               int* __restrict__ out_ti,
                                               int* __restrict__ cursor, int A) {
    int i = blockIdx.x * BLK + threadIdx.x;
    int c = (i < A) ? counts[i] : 0;
    int t = c * (c - 1);
    int lane = threadIdx.x & 63, wv = threadIdx.x >> 6;
    int ic = c, it = t;  // inclusive wave scan
    for (int off = 1; off < 64; off <<= 1) {
        int nc = __shfl_up(ic, off, 64), nt = __shfl_up(it, off, 64);
        if (lane >= off) { ic += nc; it += nt; }
    }
    __shared__ int wc[BLK / 64], wt[BLK / 64];
    if (lane == 63) { wc[wv] = ic; wt[wv] = it; }
    __syncthreads();
    int bc = 0, bt = 0;
    for (int w = 0; w < wv; ++w) { bc += wc[w]; bt += wt[w]; }
    int2 bo = partials[blockIdx.x];
    int sx = bo.x + bc + ic - c;   // exclusive
    int tx = bo.y + bt + it - t;
    if (i < A) {
        starts[i] = sx;
        tstarts[i] = tx;
        meta[i] = make_int4(c, sx, tx, 0);
        out_ti[i] = t;
        cursor[i] = sx;
    }
}

__global__ void k_scatter(const int2* __restrict__ bai, const float* __restrict__ blen,
                          const float* __restrict__ cutp, const int4* __restrict__ meta,
                          int* __restrict__ cursor, int* __restrict__ sorted_bond,
                          int* __restrict__ out_ij, int n_bond) {
    int b = blockIdx.x * blockDim.x + threadIdx.x;
    if (b >= n_bond) return;
    if (blen[b] <= *cutp) {
        int c = bai[b].x;
        int cnt = meta[c].x;
        out_ij[b] = cnt > 1 ? cnt - 1 : 0;
        int r = atomicAdd(&cursor[c], 1);   // absolute slot
        sorted_bond[r] = b;
    } else {
        out_ij[b] = 0;
    }
}

// One wave per atom, WPB atoms per block, no LDS/barriers. Wave-parallel rank
// sort (bond ids unique, c<=64 path) then coalesced int2 pair emission.
// Block 0 also writes out_ns from tstarts differences (tstarts complete here).
__global__ __launch_bounds__(WPB * 64) void k_pairs(
        const int4* __restrict__ meta, int* __restrict__ sorted_bond,
        int2* __restrict__ out_bi, const int* __restrict__ tstarts,
        const int* __restrict__ n_atoms, int* __restrict__ out_ns,
        int S, int A) {
    if (blockIdx.x == 0 && threadIdx.x < S) {
        int s = threadIdx.x;
        int blo = 0;
        for (int k = 0; k < s; ++k) blo += n_atoms[k];
        int bhi = blo + n_atoms[s];
        out_ns[s] = tstarts[bhi] - tstarts[blo];
    }

    int wv = threadIdx.x >> 6;
    int lane = threadIdx.x & 63;
    int a = blockIdx.x * WPB + wv;
    if (a >= A) return;

    int4 m = meta[a];
    int c = m.x;
    if (c < 2) return;
    int st0 = m.y;
    int P = (c * (c - 1)) >> 1;        // (i<j) combos
    int2* outp = out_bi + m.z;         // atom block: 2P int2

    if (c <= 64) {
        int v = (lane < c) ? sorted_bond[st0 + lane] : 0x7fffffff;
        int rank = 0;
        for (int j = 0; j < c; ++j) {
            int vj = __shfl(v, j, 64);
            rank += (vj < v) ? 1 : 0;
        }
        int sv = __builtin_amdgcn_ds_permute(rank << 2, v);

        int niter = (P + 63) >> 6;
        for (int it = 0; it < niter; ++it) {
            int p = (it << 6) + lane;
            bool act = p < P;
            int pp = act ? p : 0;
            int i = 0, rem = pp;
            while (rem >= c - 1 - i) { rem -= c - 1 - i; ++i; }
            int j = i + 1 + rem;
            int bi = __shfl(sv, i, 64);
            int bj = __shfl(sv, j, 64);
            if (act) {
                outp[p]     = make_int2(bi, bj);
                outp[P + p] = make_int2(bj, bi);
            }
        }
    } else if (lane == 0) {
        for (int i = 1; i < c; ++i) {
            int v = sorted_bond[st0 + i];
            int j = i - 1;
            while (j >= 0 && sorted_bond[st0 + j] > v) {
                sorted_bond[st0 + j + 1] = sorted_bond[st0 + j];
                --j;
            }
            sorted_bond[st0 + j + 1] = v;
        }
        int p = 0;
        for (int i = 0; i < c; ++i) {
            int bi = sorted_bond[st0 + i];
            for (int j = i + 1; j < c; ++j) {
                int bj = sorted_bond[st0 + j];
                outp[p]     = make_int2(bi, bj);
                outp[P + p] = make_int2(bj, bi);
                ++p;
            }
        }
    }
}

extern "C" void kernel_launch(void* const* d_in, const int* in_sizes, int n_in,
                              void* d_out, int out_size, void* d_ws, size_t ws_size,
                              hipStream_t stream) {
    const int2* bai     = (const int2*)d_in[0];   // [n_bond,2] int32
    const float* blen   = (const float*)d_in[1];  // [n_bond] f32
    const int* n_atoms  = (const int*)d_in[2];    // [S] int32
    // d_in[3] = atomic_number (unused)
    const float* cutp   = (const float*)d_in[4];  // scalar f32

    int n_bond = in_sizes[1];
    int S      = in_sizes[2];
    int A      = in_sizes[3];

    int n_tr2 = out_size - n_bond - A - S;  // 2 * n_triple

    int* out     = (int*)d_out;
    int2* out_bi = (int2*)out;          // [n_triple] pairs
    int* out_ij  = out + n_tr2;         // [n_bond]
    int* out_ti  = out_ij + n_bond;     // [A]
    int* out_ns  = out_ti + A;          // [S]

    int* ws          = (int*)d_ws;
    int* counts      = ws;
    int* cursor      = ws + A;
    int* starts      = ws + 2 * A;
    int* tstarts     = ws + 3 * A;                  // A+1, padded to 4A+4
    int4* meta       = (int4*)(ws + 4 * A + 4);     // 16B aligned
    int* sorted_bond = ws + 8 * A + 4;
    int2* partials   = (int2*)(ws + 8 * A + 4 + n_bond);

    int NB = (A + BLK - 1) / BLK;

    k_init<<<(A + 255) / 256, 256, 0, stream>>>(counts, A);
    k_count<<<(n_bond + 255) / 256, 256, 0, stream>>>(bai, blen, cutp, counts, n_bond);
    k_part<<<NB, BLK, 0, stream>>>(counts, partials, A);
    k_mid<<<1, 1024, 0, stream>>>(partials, NB, &tstarts[A]);
    k_final<<<NB, BLK, 0, stream>>>(counts, partials, starts, tstarts, meta, out_ti,
                                    cursor, A);
    k_scatter<<<(n_bond + 255) / 256, 256, 0, stream>>>(bai, blen, cutp, meta,
                                                        cursor, sorted_bond, out_ij, n_bond);
    k_pairs<<<(A + WPB - 1) / WPB, WPB * 64, 0, stream>>>(meta, sorted_bond, out_bi,
                                                          tstarts, n_atoms, out_ns, S, A);
}